// Round 17
// baseline (253.096 us; speedup 1.0000x reference)
//
#include <hip/hip_runtime.h>

typedef unsigned short u16;
typedef __attribute__((ext_vector_type(8))) short bf16x8;
typedef __attribute__((ext_vector_type(4))) float f32x4;
typedef __attribute__((ext_vector_type(4))) unsigned short u16x4;

// ---------- helpers ----------
static __device__ __forceinline__ u16 f2bf(float f) {
  unsigned int u = __builtin_bit_cast(unsigned int, f);
  u += 0x7fffu + ((u >> 16) & 1u);   // round-to-nearest-even
  return (u16)(u >> 16);
}

static __device__ __forceinline__ void load_lds16(const void* g, void* l) {
  __builtin_amdgcn_global_load_lds(
      (const __attribute__((address_space(1))) void*)g,
      (__attribute__((address_space(3))) void*)l,
      16, 0, 0);
}

// ---------- prep: bf16 convert (y<3) + 4 weight transposes (y==3) ----------
__global__ __launch_bounds__(256) void prep_kernel(
    const float* __restrict__ q, const float* __restrict__ k,
    const float* __restrict__ v,
    u16* __restrict__ qb, u16* __restrict__ kb, u16* __restrict__ vb,
    const float* __restrict__ Wq, const float* __restrict__ Wk,
    const float* __restrict__ Wv, const float* __restrict__ Wo,
    u16* __restrict__ WqT, u16* __restrict__ WkT,
    u16* __restrict__ WvT, u16* __restrict__ WoT) {
  const int z = blockIdx.y;
  if (z < 3) {
    const float* in = (z == 0) ? q : (z == 1) ? k : v;
    u16* out = (z == 0) ? qb : (z == 1) ? kb : vb;
    const int i = blockIdx.x * 256 + threadIdx.x;
    float4 f = ((const float4*)in)[i];
    u16x4 u;
    u[0] = f2bf(f.x); u[1] = f2bf(f.y); u[2] = f2bf(f.z); u[3] = f2bf(f.w);
    ((u16x4*)out)[i] = u;
    return;
  }
  const int bid = blockIdx.x;
  const int wt = bid >> 10, tile = bid & 1023;
  const float* W = (wt == 0) ? Wq : (wt == 1) ? Wk : (wt == 2) ? Wv : Wo;
  u16* WT = (wt == 0) ? WqT : (wt == 1) ? WkT : (wt == 2) ? WvT : WoT;
  __shared__ float t[32][33];
  const int tx = threadIdx.x & 31, ty = threadIdx.x >> 5;
  const int bx = (tile & 31) * 32, by = (tile >> 5) * 32;
#pragma unroll
  for (int r = ty; r < 32; r += 8) t[r][tx] = W[(size_t)(by + r) * 1024 + bx + tx];
  __syncthreads();
#pragma unroll
  for (int r = ty; r < 32; r += 8) WT[(size_t)(bx + r) * 1024 + by + tx] = f2bf(t[tx][r]);
}

// ---------- shared 128x128x(BK=32) bf16 GEMM core (K = 1024) ----------
__device__ __forceinline__ void gemm_core(const u16* __restrict__ A,
                                          const u16* __restrict__ BT,
                                          int m0, int n0,
                                          u16* As, u16* Bs, f32x4 acc[4][4]) {
  const int tid = threadIdx.x;
  const int w = tid >> 6, l = tid & 63;
  const int lr = l & 15, lg = l >> 4;
  const int wm = w >> 1, wn = w & 1;

  const int p0 = tid * 16, p1 = p0 + 4096;   // byte index within 8KB tile
  const char* gA0 = (const char*)A + (size_t)(m0 + (p0 >> 6)) * 2048 + (p0 & 63);
  const char* gA1 = (const char*)A + (size_t)(m0 + (p1 >> 6)) * 2048 + (p1 & 63);
  const char* gB0 = (const char*)BT + (size_t)(n0 + (p0 >> 6)) * 2048 + (p0 & 63);
  const char* gB1 = (const char*)BT + (size_t)(n0 + (p1 >> 6)) * 2048 + (p1 & 63);

#define GCSTAGE(bb, kb)                                                      \
  load_lds16(gA0 + (kb), (char*)As + (bb) * 8192 + w * 1024);                \
  load_lds16(gA1 + (kb), (char*)As + (bb) * 8192 + 4096 + w * 1024);         \
  load_lds16(gB0 + (kb), (char*)Bs + (bb) * 8192 + w * 1024);                \
  load_lds16(gB1 + (kb), (char*)Bs + (bb) * 8192 + 4096 + w * 1024);

  GCSTAGE(0, 0);
  __syncthreads();
  for (int kt = 0; kt < 32; ++kt) {
    const int bb = kt & 1;
    if (kt < 31) { GCSTAGE(bb ^ 1, (kt + 1) * 64); }
    const u16* as = As + bb * 4096;
    const u16* bs = Bs + bb * 4096;
    bf16x8 av[4], bv[4];
#pragma unroll
    for (int f = 0; f < 4; ++f) {
      av[f] = *(const bf16x8*)(as + (wm * 64 + f * 16 + lr) * 32 + lg * 8);
      bv[f] = *(const bf16x8*)(bs + (wn * 64 + f * 16 + lr) * 32 + lg * 8);
    }
#pragma unroll
    for (int fm = 0; fm < 4; ++fm)
#pragma unroll
      for (int fn = 0; fn < 4; ++fn)
        acc[fm][fn] = __builtin_amdgcn_mfma_f32_16x16x32_bf16(av[fm], bv[fn],
                                                              acc[fm][fn], 0, 0, 0);
    asm volatile("s_waitcnt vmcnt(0)" ::: "memory");
    __builtin_amdgcn_sched_barrier(0);
    __builtin_amdgcn_s_barrier();
  }
#undef GCSTAGE
}

// ---------- 64(M)x128(N)x(BK=32) core -- higher-occupancy variant ----------
__device__ __forceinline__ void gemm_core64(const u16* __restrict__ A,
                                            const u16* __restrict__ BT,
                                            int m0, int n0,
                                            u16* As, u16* Bs, f32x4 acc[2][4]) {
  const int tid = threadIdx.x;
  const int w = tid >> 6, l = tid & 63;
  const int lr = l & 15, lg = l >> 4;
  const int wm = w >> 1, wn = w & 1;

  const int pA = tid * 16;                    // A: 4KB, one load/thread
  const int pB0 = tid * 16, pB1 = pB0 + 4096; // B: 8KB, two loads/thread
  const char* gA = (const char*)A + (size_t)(m0 + (pA >> 6)) * 2048 + (pA & 63);
  const char* gB0 = (const char*)BT + (size_t)(n0 + (pB0 >> 6)) * 2048 + (pB0 & 63);
  const char* gB1 = (const char*)BT + (size_t)(n0 + (pB1 >> 6)) * 2048 + (pB1 & 63);

#define GC64STAGE(bb, kb)                                                    \
  load_lds16(gA + (kb), (char*)As + (bb) * 4096 + w * 1024);                 \
  load_lds16(gB0 + (kb), (char*)Bs + (bb) * 8192 + w * 1024);                \
  load_lds16(gB1 + (kb), (char*)Bs + (bb) * 8192 + 4096 + w * 1024);

  GC64STAGE(0, 0);
  __syncthreads();
  for (int kt = 0; kt < 32; ++kt) {
    const int bb = kt & 1;
    if (kt < 31) { GC64STAGE(bb ^ 1, (kt + 1) * 64); }
    const u16* as = As + bb * 2048;
    const u16* bs = Bs + bb * 4096;
    bf16x8 av[2], bv[4];
#pragma unroll
    for (int f = 0; f < 2; ++f)
      av[f] = *(const bf16x8*)(as + (wm * 32 + f * 16 + lr) * 32 + lg * 8);
#pragma unroll
    for (int f = 0; f < 4; ++f)
      bv[f] = *(const bf16x8*)(bs + (wn * 64 + f * 16 + lr) * 32 + lg * 8);
#pragma unroll
    for (int fm = 0; fm < 2; ++fm)
#pragma unroll
      for (int fn = 0; fn < 4; ++fn)
        acc[fm][fn] = __builtin_amdgcn_mfma_f32_16x16x32_bf16(av[fm], bv[fn],
                                                              acc[fm][fn], 0, 0, 0);
    asm volatile("s_waitcnt vmcnt(0)" ::: "memory");
    __builtin_amdgcn_sched_barrier(0);
    __builtin_amdgcn_s_barrier();
  }
#undef GC64STAGE
}

// ---------- QKV projection GEMM ----------
__global__ __launch_bounds__(256) void qkv_gemm(
    const u16* __restrict__ qb, const u16* __restrict__ kbm, const u16* __restrict__ vbm,
    const u16* __restrict__ WqT, const u16* __restrict__ WkT, const u16* __restrict__ WvT,
    const float* __restrict__ bq, const float* __restrict__ bk, const float* __restrict__ bv,
    u16* __restrict__ Qb, u16* __restrict__ Kb, u16* __restrict__ Vt) {
  __shared__ u16 As[2 * 4096], Bs[2 * 4096];
  const int z = blockIdx.z;
  const u16* A = (z == 0) ? qb : (z == 1) ? kbm : vbm;
  const u16* BT = (z == 0) ? WqT : (z == 1) ? WkT : WvT;
  const float* bias = (z == 0) ? bq : (z == 1) ? bk : bv;
  const int m0 = blockIdx.x * 128, n0 = blockIdx.y * 128;

  f32x4 acc[4][4];
#pragma unroll
  for (int i = 0; i < 4; ++i)
#pragma unroll
    for (int j = 0; j < 4; ++j) acc[i][j] = (f32x4){0.f, 0.f, 0.f, 0.f};

  gemm_core(A, BT, m0, n0, As, Bs, acc);

  const int tid = threadIdx.x;
  const int w = tid >> 6, l = tid & 63, lr = l & 15, lg = l >> 4;
  const int wm = w >> 1, wn = w & 1;
#pragma unroll
  for (int fm = 0; fm < 4; ++fm)
#pragma unroll
    for (int fn = 0; fn < 4; ++fn)
#pragma unroll
      for (int r = 0; r < 4; ++r) {
        const int m = m0 + wm * 64 + fm * 16 + lg * 4 + r;
        const int n = n0 + wn * 64 + fn * 16 + lr;
        const float val = acc[fm][fn][r] + bias[n];
        const int b = m >> 11, s = m & 2047, hh = n >> 6, d = n & 63;
        const u16 u = f2bf(val);
        if (z == 2)
          Vt[(((size_t)b * 16 + hh) * 64 + d) * 2048 + s] = u;
        else if (z == 0)
          Qb[(((size_t)b * 16 + hh) * 2048 + s) * 64 + d] = u;
        else
          Kb[(((size_t)b * 16 + hh) * 2048 + s) * 64 + d] = u;
      }
}

// ---------- output projection GEMM (+bias +residual), 64x128 tiles ----------
__global__ __launch_bounds__(256) void o_gemm(
    const u16* __restrict__ Ao, const u16* __restrict__ WoT,
    const float* __restrict__ bo, const float* __restrict__ resid,
    float* __restrict__ x) {
  __shared__ u16 As[2 * 2048], Bs[2 * 4096];
  const int m0 = blockIdx.x * 64, n0 = blockIdx.y * 128;
  f32x4 acc[2][4];
#pragma unroll
  for (int i = 0; i < 2; ++i)
#pragma unroll
    for (int j = 0; j < 4; ++j) acc[i][j] = (f32x4){0.f, 0.f, 0.f, 0.f};

  gemm_core64(Ao, WoT, m0, n0, As, Bs, acc);

  const int tid = threadIdx.x;
  const int w = tid >> 6, l = tid & 63, lr = l & 15, lg = l >> 4;
  const int wm = w >> 1, wn = w & 1;
#pragma unroll
  for (int fm = 0; fm < 2; ++fm)
#pragma unroll
    for (int fn = 0; fn < 4; ++fn)
#pragma unroll
      for (int r = 0; r < 4; ++r) {
        const int m = m0 + wm * 32 + fm * 16 + lg * 4 + r;
        const int n = n0 + wn * 64 + fn * 16 + lr;
        const size_t idx = (size_t)m * 1024 + n;
        x[idx] = acc[fm][fn][r] + bo[n] + resid[idx];
      }
}

// ---------- softmax denominators, GEMM-shaped ----------
__global__ __launch_bounds__(256, 4) void denom_kernel(
    const u16* __restrict__ Qb, const u16* __restrict__ Kb,
    float* __restrict__ Ld) {
  __shared__ u16 Kbuf[2][4096];   // [64 j][64 d] bf16, swizzled
  const int tid = threadIdx.x;
  const int w = tid >> 6, l = tid & 63, lr = l & 15, lg = l >> 4;

  int flat = blockIdx.x;
  flat = (flat & 7) * 64 + (flat >> 3);   // bijective XCD swizzle (512=8*64)
  const int it = flat & 15, bh = flat >> 4;
  const int i0 = it * 128;

  const char* KhB = (const char*)(Kb + (size_t)bh * 2048 * 64);
  const u16* Q0 = Qb + ((size_t)bh * 2048 + i0 + w * 32 + lr) * 64;
  const bf16x8 q00 = *(const bf16x8*)(Q0 + lg * 8);
  const bf16x8 q01 = *(const bf16x8*)(Q0 + 32 + lg * 8);
  const bf16x8 q10 = *(const bf16x8*)(Q0 + 16 * 64 + lg * 8);
  const bf16x8 q11 = *(const bf16x8*)(Q0 + 16 * 64 + 32 + lg * 8);

  const int srow = l >> 3;
  const int soff = ((l & 7) ^ srow) << 4;
  const int rsw = (lr & 7) << 4;

#define STAGE_K(bb, j0)                                                      \
  load_lds16(KhB + (size_t)((j0) + w * 8 + srow) * 128 + soff,               \
             (char*)Kbuf[bb] + w * 1024);                                    \
  load_lds16(KhB + (size_t)((j0) + 32 + w * 8 + srow) * 128 + soff,          \
             (char*)Kbuf[bb] + w * 1024 + 4096);

  f32x4 ls0 = (f32x4){0.f, 0.f, 0.f, 0.f}, ls1 = ls0;
  STAGE_K(0, 0);
  __syncthreads();
  for (int jt = 0; jt < 32; ++jt) {
    const int bb = jt & 1;
    if (jt < 31) { STAGE_K(bb ^ 1, (jt + 1) * 64); }
    const char* kb = (const char*)Kbuf[bb];
#pragma unroll
    for (int t = 0; t < 4; ++t) {
      const bf16x8 k0 = *(const bf16x8*)(kb + (t * 16 + lr) * 128 + ((lg * 16) ^ rsw));
      const bf16x8 k1 = *(const bf16x8*)(kb + (t * 16 + lr) * 128 + ((64 + lg * 16) ^ rsw));
      f32x4 c0 = (f32x4){0.f, 0.f, 0.f, 0.f}, c1 = c0;
      c0 = __builtin_amdgcn_mfma_f32_16x16x32_bf16(k0, q00, c0, 0, 0, 0);
      c0 = __builtin_amdgcn_mfma_f32_16x16x32_bf16(k1, q01, c0, 0, 0, 0);
      c1 = __builtin_amdgcn_mfma_f32_16x16x32_bf16(k0, q10, c1, 0, 0, 0);
      c1 = __builtin_amdgcn_mfma_f32_16x16x32_bf16(k1, q11, c1, 0, 0, 0);
      ls0[0] += __expf(c0[0] * 0.125f);
      ls0[1] += __expf(c0[1] * 0.125f);
      ls0[2] += __expf(c0[2] * 0.125f);
      ls0[3] += __expf(c0[3] * 0.125f);
      ls1[0] += __expf(c1[0] * 0.125f);
      ls1[1] += __expf(c1[1] * 0.125f);
      ls1[2] += __expf(c1[2] * 0.125f);
      ls1[3] += __expf(c1[3] * 0.125f);
    }
    __syncthreads();
  }
#undef STAGE_K
  float s0 = ls0[0] + ls0[1] + ls0[2] + ls0[3];
  s0 += __shfl_xor(s0, 16);
  s0 += __shfl_xor(s0, 32);
  float s1 = ls1[0] + ls1[1] + ls1[2] + ls1[3];
  s1 += __shfl_xor(s1, 16);
  s1 += __shfl_xor(s1, 32);
  if (l < 16) {
    Ld[(size_t)bh * 2048 + i0 + w * 32 + l] = s0;
    Ld[(size_t)bh * 2048 + i0 + w * 32 + 16 + l] = s1;
  }
}

// ---------- fused attention, 8-wave blocks, triple-buffered tiles ----------
// R17: K/V tiles are TRIPLE-buffered (stage jt+2 during iter jt) and the
// barrier wait is vmcnt(10): from newest the FIFO holds [4 stores jt]
// [2 loads jt][4 stores jt-1] = 10, so the wait drains loads(jt-1) (the
// buffer read next iteration) and stores(jt-2), while stores(jt-1) keep
// flying -- NT stores now get TWO iterations to retire instead of one,
// decoupling HBM write-burst variance from the loop period. LDS 64KB ->
// still 2 blocks/CU x 8 waves.
__global__ __launch_bounds__(512, 4) void attn3_kernel(
    const u16* __restrict__ Qb, const u16* __restrict__ Kb,
    const u16* __restrict__ Vt, const float* __restrict__ Ld,
    float* __restrict__ attnG, u16* __restrict__ outattn) {
  __shared__ u16 Kbuf[3][4096];   // [64 j][64 d] bf16, swizzled, 8KB each
  __shared__ u16 Vbuf[3][4096];   // [64 d][64 j] bf16, swizzled, 8KB each
  __shared__ u16 Pbuf[8][1024];   // per-wave [16 q][64 j] bf16, swizzled
  const int tid = threadIdx.x;
  const int w = tid >> 6, l = tid & 63, lr = l & 15, lg = l >> 4;

  int flat = (blockIdx.z * 16 + blockIdx.y) * 16 + blockIdx.x;
  flat = (flat & 7) * 64 + (flat >> 3);           // bijective XCD swizzle (512)
  const int qt = flat & 15, h = (flat >> 4) & 15, b = flat >> 8;
  const int bh = b * 16 + h;
  const int i0 = qt * 128 + w * 16;

  const char* KhB = (const char*)(Kb + (size_t)bh * 2048 * 64);
  const char* VhB = (const char*)(Vt + (size_t)bh * 64 * 2048);
  const u16* Qrow = Qb + ((size_t)bh * 2048 + i0 + lr) * 64;
  const bf16x8 bq0 = *(const bf16x8*)(Qrow + lg * 8);
  const bf16x8 bq1 = *(const bf16x8*)(Qrow + 32 + lg * 8);
  const float inv = 1.f / Ld[(size_t)bh * 2048 + i0 + lr];

  const int srow = l >> 3;                 // row-within-8 for this lane
  const int soff = ((l & 7) ^ srow) << 4;  // logical byte offset fetched
  const int rsw = (lr & 7) << 4;           // read-side swizzle for frags

  // 8 waves cover the full 64 rows of each tile: wave w -> rows w*8+srow.
#define STAGE_K(bb, j0)                                                      \
  load_lds16(KhB + (size_t)((j0) + w * 8 + srow) * 128 + soff,               \
             (char*)Kbuf[bb] + w * 1024);
#define STAGE_V(bb, j0)                                                      \
  load_lds16(VhB + (size_t)(w * 8 + srow) * 4096 + (size_t)(j0) * 2 + soff,  \
             (char*)Vbuf[bb] + w * 1024);

  // coalesced attn store base: lane l -> row (l>>4), col (l&15)*4
  float* const awb = attnG + ((size_t)bh * 2048 + i0 + (l >> 4)) * 2048 + (l & 15) * 4;
  char* const Pw = (char*)Pbuf[w];
  f32x4 o0 = (f32x4){0.f, 0.f, 0.f, 0.f}, o1 = o0, o2 = o0, o3 = o0;

  STAGE_K(0, 0);
  STAGE_V(0, 0);
  STAGE_K(1, 64);
  STAGE_V(1, 64);
  __syncthreads();
  for (int jt = 0; jt < 32; ++jt) {
    const int bb = jt % 3;
    if (jt < 30) {
      const int sb = (jt + 2) % 3;
      STAGE_K(sb, (jt + 2) * 64);
      STAGE_V(sb, (jt + 2) * 64);
    }
    const char* kb = (const char*)Kbuf[bb];
    const char* vb = (const char*)Vbuf[bb];
    const int j0 = jt * 64;
    // scores -> P (bf16, swizzled LDS)
#pragma unroll
    for (int t = 0; t < 4; ++t) {
      const bf16x8 k0 = *(const bf16x8*)(kb + (t * 16 + lr) * 128 + ((lg * 16) ^ rsw));
      const bf16x8 k1 = *(const bf16x8*)(kb + (t * 16 + lr) * 128 + ((64 + lg * 16) ^ rsw));
      f32x4 c = (f32x4){0.f, 0.f, 0.f, 0.f};
      c = __builtin_amdgcn_mfma_f32_16x16x32_bf16(k0, bq0, c, 0, 0, 0);
      c = __builtin_amdgcn_mfma_f32_16x16x32_bf16(k1, bq1, c, 0, 0, 0);
      u16x4 pu;
      pu[0] = f2bf(__expf(c[0] * 0.125f) * inv);
      pu[1] = f2bf(__expf(c[1] * 0.125f) * inv);
      pu[2] = f2bf(__expf(c[2] * 0.125f) * inv);
      pu[3] = f2bf(__expf(c[3] * 0.125f) * inv);
      *(u16x4*)(Pw + lr * 128 + ((t * 32 + lg * 8) ^ rsw)) = pu;
    }
    // coalesced attn write-back from P: 4 instrs, each 4 x 256B contiguous
#pragma unroll
    for (int rq = 0; rq < 4; ++rq) {
      const int row = rq * 4 + (l >> 4);
      const u16x4 pb = *(const u16x4*)(Pw + row * 128 +
                                       (((l & 15) * 8) ^ ((row & 7) << 4)));
      f32x4 pf;
      pf[0] = __builtin_bit_cast(float, (unsigned)(unsigned short)pb[0] << 16);
      pf[1] = __builtin_bit_cast(float, (unsigned)(unsigned short)pb[1] << 16);
      pf[2] = __builtin_bit_cast(float, (unsigned)(unsigned short)pb[2] << 16);
      pf[3] = __builtin_bit_cast(float, (unsigned)(unsigned short)pb[3] << 16);
      __builtin_nontemporal_store(pf, (f32x4*)(awb + (size_t)(rq * 4) * 2048 + j0));
    }
    // PV (MFMA cluster -- setprio per T5)
    __builtin_amdgcn_s_setprio(1);
#pragma unroll
    for (int half = 0; half < 2; ++half) {
      const int jjb = half * 64;   // byte offset of 32-j half within P/V rows
      const bf16x8 pa = *(const bf16x8*)(Pw + lr * 128 + ((jjb + lg * 16) ^ rsw));
      const bf16x8 v0 = *(const bf16x8*)(vb + (0 * 16 + lr) * 128 + ((jjb + lg * 16) ^ rsw));
      const bf16x8 v1 = *(const bf16x8*)(vb + (1 * 16 + lr) * 128 + ((jjb + lg * 16) ^ rsw));
      const bf16x8 v2 = *(const bf16x8*)(vb + (2 * 16 + lr) * 128 + ((jjb + lg * 16) ^ rsw));
      const bf16x8 v3 = *(const bf16x8*)(vb + (3 * 16 + lr) * 128 + ((jjb + lg * 16) ^ rsw));
      o0 = __builtin_amdgcn_mfma_f32_16x16x32_bf16(pa, v0, o0, 0, 0, 0);
      o1 = __builtin_amdgcn_mfma_f32_16x16x32_bf16(pa, v1, o1, 0, 0, 0);
      o2 = __builtin_amdgcn_mfma_f32_16x16x32_bf16(pa, v2, o2, 0, 0, 0);
      o3 = __builtin_amdgcn_mfma_f32_16x16x32_bf16(pa, v3, o3, 0, 0, 0);
    }
    __builtin_amdgcn_s_setprio(0);
    // vmcnt(10): keep [4 stores jt][2 loads jt][4 stores jt-1] in flight;
    // drain loads(jt-1) (buffer for iter jt+1) and stores(jt-2).
    asm volatile("s_waitcnt vmcnt(10)" ::: "memory");
    __builtin_amdgcn_sched_barrier(0);
    __builtin_amdgcn_s_barrier();
  }
#undef STAGE_K
#undef STAGE_V

  // ---- O write: lane holds O[i=lg*4+r][d = dblk*16 + lr] ----
#pragma unroll
  for (int r = 0; r < 4; ++r) {
    u16* orow = outattn + ((size_t)b * 2048 + i0 + lg * 4 + r) * 1024 + h * 64 + lr;
    orow[0]  = f2bf(o0[r]);
    orow[16] = f2bf(o1[r]);
    orow[32] = f2bf(o2[r]);
    orow[48] = f2bf(o3[r]);
  }
}

// ---------- LayerNorm ----------
__global__ __launch_bounds__(256) void ln_kernel(const float* __restrict__ x,
                                                 const float* __restrict__ gamma,
                                                 const float* __restrict__ beta,
                                                 float* __restrict__ y) {
  const int row = blockIdx.x, t = threadIdx.x;
  const float4 xv = *(const float4*)(x + (size_t)row * 1024 + t * 4);
  float s = xv.x + xv.y + xv.z + xv.w;
  float q2 = xv.x * xv.x + xv.y * xv.y + xv.z * xv.z + xv.w * xv.w;
#pragma unroll
  for (int off = 32; off >= 1; off >>= 1) {
    s += __shfl_xor(s, off);
    q2 += __shfl_xor(q2, off);
  }
  __shared__ float ps[4], pq[4];
  const int w = t >> 6, l = t & 63;
  if (l == 0) { ps[w] = s; pq[w] = q2; }
  __syncthreads();
  s = ps[0] + ps[1] + ps[2] + ps[3];
  q2 = pq[0] + pq[1] + pq[2] + pq[3];
  const float mu = s * (1.f / 1024.f);
  const float var = q2 * (1.f / 1024.f) - mu * mu;
  const float rs = rsqrtf(var + 1e-5f);
  const float4 g = *(const float4*)(gamma + t * 4);
  const float4 bb = *(const float4*)(beta + t * 4);
  float4 o;
  o.x = (xv.x - mu) * rs * g.x + bb.x;
  o.y = (xv.y - mu) * rs * g.y + bb.y;
  o.z = (xv.z - mu) * rs * g.z + bb.z;
  o.w = (xv.w - mu) * rs * g.w + bb.w;
  *(float4*)(y + (size_t)row * 1024 + t * 4) = o;
}

// ---------- launch ----------
extern "C" void kernel_launch(void* const* d_in, const int* in_sizes, int n_in,
                              void* d_out, int out_size, void* d_ws, size_t ws_size,
                              hipStream_t stream) {
  (void)in_sizes; (void)n_in; (void)out_size; (void)ws_size;
  const float* q = (const float*)d_in[0];
  const float* k = (const float*)d_in[1];
  const float* v = (const float*)d_in[2];
  const float* Wq = (const float*)d_in[3];
  const float* bq = (const float*)d_in[4];
  const float* Wk = (const float*)d_in[5];
  const float* bk = (const float*)d_in[6];
  const float* Wv = (const float*)d_in[7];
  const float* bv = (const float*)d_in[8];
  const float* Wo = (const float*)d_in[9];
  const float* bo = (const float*)d_in[10];
  const float* gamma = (const float*)d_in[11];
  const float* beta = (const float*)d_in[12];

  char* ws = (char*)d_ws;
  const size_t MB = 1ull << 20;
  u16* WqT = (u16*)(ws + 0 * MB);
  u16* WkT = (u16*)(ws + 2 * MB);
  u16* WvT = (u16*)(ws + 4 * MB);
  u16* WoT = (u16*)(ws + 6 * MB);
  u16* qb  = (u16*)(ws + 8 * MB);
  float* Ld = (float*)(ws + 10 * MB);   // 32*2048 f32 = 256KB (gap 10-16MB)
  u16* kb  = (u16*)(ws + 16 * MB);
  u16* vb  = (u16*)(ws + 24 * MB);
  u16* Qb  = (u16*)(ws + 32 * MB);
  u16* Kb  = (u16*)(ws + 40 * MB);
  u16* Vt  = (u16*)(ws + 48 * MB);
  u16* oa  = (u16*)(ws + 56 * MB);
  float* x = (float*)(ws + 64 * MB);

  float* y = (float*)d_out;
  float* attnG = y + 4194304;  // 2*2048*1024

  prep_kernel<<<dim3(4096, 4), 256, 0, stream>>>(q, k, v, qb, kb, vb,
                                                 Wq, Wk, Wv, Wo,
                                                 WqT, WkT, WvT, WoT);
  qkv_gemm<<<dim3(32, 8, 3), 256, 0, stream>>>(qb, kb, vb, WqT, WkT, WvT,
                                               bq, bk, bv, Qb, Kb, Vt);
  denom_kernel<<<512, 256, 0, stream>>>(Qb, Kb, Ld);
  attn3_kernel<<<dim3(16, 16, 2), 512, 0, stream>>>(Qb, Kb, Vt, Ld, attnG, oa);
  o_gemm<<<dim3(64, 8), 256, 0, stream>>>(oa, WoT, bo, q, x);
  ln_kernel<<<4096, 256, 0, stream>>>(x, gamma, beta, y);
}

// Round 18
// 251.773 us; speedup vs baseline: 1.0053x; 1.0053x over previous
//
#include <hip/hip_runtime.h>

typedef unsigned short u16;
typedef __attribute__((ext_vector_type(8))) short bf16x8;
typedef __attribute__((ext_vector_type(4))) float f32x4;
typedef __attribute__((ext_vector_type(4))) unsigned short u16x4;

// ---------- helpers ----------
static __device__ __forceinline__ u16 f2bf(float f) {
  unsigned int u = __builtin_bit_cast(unsigned int, f);
  u += 0x7fffu + ((u >> 16) & 1u);   // round-to-nearest-even
  return (u16)(u >> 16);
}

static __device__ __forceinline__ void load_lds16(const void* g, void* l) {
  __builtin_amdgcn_global_load_lds(
      (const __attribute__((address_space(1))) void*)g,
      (__attribute__((address_space(3))) void*)l,
      16, 0, 0);
}

// ---------- prep: bf16 convert (y<3) + 4 weight transposes (y==3) ----------
__global__ __launch_bounds__(256) void prep_kernel(
    const float* __restrict__ q, const float* __restrict__ k,
    const float* __restrict__ v,
    u16* __restrict__ qb, u16* __restrict__ kb, u16* __restrict__ vb,
    const float* __restrict__ Wq, const float* __restrict__ Wk,
    const float* __restrict__ Wv, const float* __restrict__ Wo,
    u16* __restrict__ WqT, u16* __restrict__ WkT,
    u16* __restrict__ WvT, u16* __restrict__ WoT) {
  const int z = blockIdx.y;
  if (z < 3) {
    const float* in = (z == 0) ? q : (z == 1) ? k : v;
    u16* out = (z == 0) ? qb : (z == 1) ? kb : vb;
    const int i = blockIdx.x * 256 + threadIdx.x;
    float4 f = ((const float4*)in)[i];
    u16x4 u;
    u[0] = f2bf(f.x); u[1] = f2bf(f.y); u[2] = f2bf(f.z); u[3] = f2bf(f.w);
    ((u16x4*)out)[i] = u;
    return;
  }
  const int bid = blockIdx.x;
  const int wt = bid >> 10, tile = bid & 1023;
  const float* W = (wt == 0) ? Wq : (wt == 1) ? Wk : (wt == 2) ? Wv : Wo;
  u16* WT = (wt == 0) ? WqT : (wt == 1) ? WkT : (wt == 2) ? WvT : WoT;
  __shared__ float t[32][33];
  const int tx = threadIdx.x & 31, ty = threadIdx.x >> 5;
  const int bx = (tile & 31) * 32, by = (tile >> 5) * 32;
#pragma unroll
  for (int r = ty; r < 32; r += 8) t[r][tx] = W[(size_t)(by + r) * 1024 + bx + tx];
  __syncthreads();
#pragma unroll
  for (int r = ty; r < 32; r += 8) WT[(size_t)(bx + r) * 1024 + by + tx] = f2bf(t[tx][r]);
}

// ---------- shared 128x128x(BK=32) bf16 GEMM core (K = 1024) ----------
__device__ __forceinline__ void gemm_core(const u16* __restrict__ A,
                                          const u16* __restrict__ BT,
                                          int m0, int n0,
                                          u16* As, u16* Bs, f32x4 acc[4][4]) {
  const int tid = threadIdx.x;
  const int w = tid >> 6, l = tid & 63;
  const int lr = l & 15, lg = l >> 4;
  const int wm = w >> 1, wn = w & 1;

  const int p0 = tid * 16, p1 = p0 + 4096;   // byte index within 8KB tile
  const char* gA0 = (const char*)A + (size_t)(m0 + (p0 >> 6)) * 2048 + (p0 & 63);
  const char* gA1 = (const char*)A + (size_t)(m0 + (p1 >> 6)) * 2048 + (p1 & 63);
  const char* gB0 = (const char*)BT + (size_t)(n0 + (p0 >> 6)) * 2048 + (p0 & 63);
  const char* gB1 = (const char*)BT + (size_t)(n0 + (p1 >> 6)) * 2048 + (p1 & 63);

#define GCSTAGE(bb, kb)                                                      \
  load_lds16(gA0 + (kb), (char*)As + (bb) * 8192 + w * 1024);                \
  load_lds16(gA1 + (kb), (char*)As + (bb) * 8192 + 4096 + w * 1024);         \
  load_lds16(gB0 + (kb), (char*)Bs + (bb) * 8192 + w * 1024);                \
  load_lds16(gB1 + (kb), (char*)Bs + (bb) * 8192 + 4096 + w * 1024);

  GCSTAGE(0, 0);
  __syncthreads();
  for (int kt = 0; kt < 32; ++kt) {
    const int bb = kt & 1;
    if (kt < 31) { GCSTAGE(bb ^ 1, (kt + 1) * 64); }
    const u16* as = As + bb * 4096;
    const u16* bs = Bs + bb * 4096;
    bf16x8 av[4], bv[4];
#pragma unroll
    for (int f = 0; f < 4; ++f) {
      av[f] = *(const bf16x8*)(as + (wm * 64 + f * 16 + lr) * 32 + lg * 8);
      bv[f] = *(const bf16x8*)(bs + (wn * 64 + f * 16 + lr) * 32 + lg * 8);
    }
#pragma unroll
    for (int fm = 0; fm < 4; ++fm)
#pragma unroll
      for (int fn = 0; fn < 4; ++fn)
        acc[fm][fn] = __builtin_amdgcn_mfma_f32_16x16x32_bf16(av[fm], bv[fn],
                                                              acc[fm][fn], 0, 0, 0);
    asm volatile("s_waitcnt vmcnt(0)" ::: "memory");
    __builtin_amdgcn_sched_barrier(0);
    __builtin_amdgcn_s_barrier();
  }
#undef GCSTAGE
}

// ---------- 64(M)x128(N)x(BK=32) core -- higher-occupancy variant ----------
__device__ __forceinline__ void gemm_core64(const u16* __restrict__ A,
                                            const u16* __restrict__ BT,
                                            int m0, int n0,
                                            u16* As, u16* Bs, f32x4 acc[2][4]) {
  const int tid = threadIdx.x;
  const int w = tid >> 6, l = tid & 63;
  const int lr = l & 15, lg = l >> 4;
  const int wm = w >> 1, wn = w & 1;

  const int pA = tid * 16;                    // A: 4KB, one load/thread
  const int pB0 = tid * 16, pB1 = pB0 + 4096; // B: 8KB, two loads/thread
  const char* gA = (const char*)A + (size_t)(m0 + (pA >> 6)) * 2048 + (pA & 63);
  const char* gB0 = (const char*)BT + (size_t)(n0 + (pB0 >> 6)) * 2048 + (pB0 & 63);
  const char* gB1 = (const char*)BT + (size_t)(n0 + (pB1 >> 6)) * 2048 + (pB1 & 63);

#define GC64STAGE(bb, kb)                                                    \
  load_lds16(gA + (kb), (char*)As + (bb) * 4096 + w * 1024);                 \
  load_lds16(gB0 + (kb), (char*)Bs + (bb) * 8192 + w * 1024);                \
  load_lds16(gB1 + (kb), (char*)Bs + (bb) * 8192 + 4096 + w * 1024);

  GC64STAGE(0, 0);
  __syncthreads();
  for (int kt = 0; kt < 32; ++kt) {
    const int bb = kt & 1;
    if (kt < 31) { GC64STAGE(bb ^ 1, (kt + 1) * 64); }
    const u16* as = As + bb * 2048;
    const u16* bs = Bs + bb * 4096;
    bf16x8 av[2], bv[4];
#pragma unroll
    for (int f = 0; f < 2; ++f)
      av[f] = *(const bf16x8*)(as + (wm * 32 + f * 16 + lr) * 32 + lg * 8);
#pragma unroll
    for (int f = 0; f < 4; ++f)
      bv[f] = *(const bf16x8*)(bs + (wn * 64 + f * 16 + lr) * 32 + lg * 8);
#pragma unroll
    for (int fm = 0; fm < 2; ++fm)
#pragma unroll
      for (int fn = 0; fn < 4; ++fn)
        acc[fm][fn] = __builtin_amdgcn_mfma_f32_16x16x32_bf16(av[fm], bv[fn],
                                                              acc[fm][fn], 0, 0, 0);
    asm volatile("s_waitcnt vmcnt(0)" ::: "memory");
    __builtin_amdgcn_sched_barrier(0);
    __builtin_amdgcn_s_barrier();
  }
#undef GC64STAGE
}

// ---------- QKV projection GEMM ----------
__global__ __launch_bounds__(256) void qkv_gemm(
    const u16* __restrict__ qb, const u16* __restrict__ kbm, const u16* __restrict__ vbm,
    const u16* __restrict__ WqT, const u16* __restrict__ WkT, const u16* __restrict__ WvT,
    const float* __restrict__ bq, const float* __restrict__ bk, const float* __restrict__ bv,
    u16* __restrict__ Qb, u16* __restrict__ Kb, u16* __restrict__ Vt) {
  __shared__ u16 As[2 * 4096], Bs[2 * 4096];
  const int z = blockIdx.z;
  const u16* A = (z == 0) ? qb : (z == 1) ? kbm : vbm;
  const u16* BT = (z == 0) ? WqT : (z == 1) ? WkT : WvT;
  const float* bias = (z == 0) ? bq : (z == 1) ? bk : bv;
  const int m0 = blockIdx.x * 128, n0 = blockIdx.y * 128;

  f32x4 acc[4][4];
#pragma unroll
  for (int i = 0; i < 4; ++i)
#pragma unroll
    for (int j = 0; j < 4; ++j) acc[i][j] = (f32x4){0.f, 0.f, 0.f, 0.f};

  gemm_core(A, BT, m0, n0, As, Bs, acc);

  const int tid = threadIdx.x;
  const int w = tid >> 6, l = tid & 63, lr = l & 15, lg = l >> 4;
  const int wm = w >> 1, wn = w & 1;
#pragma unroll
  for (int fm = 0; fm < 4; ++fm)
#pragma unroll
    for (int fn = 0; fn < 4; ++fn)
#pragma unroll
      for (int r = 0; r < 4; ++r) {
        const int m = m0 + wm * 64 + fm * 16 + lg * 4 + r;
        const int n = n0 + wn * 64 + fn * 16 + lr;
        const float val = acc[fm][fn][r] + bias[n];
        const int b = m >> 11, s = m & 2047, hh = n >> 6, d = n & 63;
        const u16 u = f2bf(val);
        if (z == 2)
          Vt[(((size_t)b * 16 + hh) * 64 + d) * 2048 + s] = u;
        else if (z == 0)
          Qb[(((size_t)b * 16 + hh) * 2048 + s) * 64 + d] = u;
        else
          Kb[(((size_t)b * 16 + hh) * 2048 + s) * 64 + d] = u;
      }
}

// ---------- output projection GEMM (+bias +residual), 64x128 tiles ----------
__global__ __launch_bounds__(256) void o_gemm(
    const u16* __restrict__ Ao, const u16* __restrict__ WoT,
    const float* __restrict__ bo, const float* __restrict__ resid,
    float* __restrict__ x) {
  __shared__ u16 As[2 * 2048], Bs[2 * 4096];
  const int m0 = blockIdx.x * 64, n0 = blockIdx.y * 128;
  f32x4 acc[2][4];
#pragma unroll
  for (int i = 0; i < 2; ++i)
#pragma unroll
    for (int j = 0; j < 4; ++j) acc[i][j] = (f32x4){0.f, 0.f, 0.f, 0.f};

  gemm_core64(Ao, WoT, m0, n0, As, Bs, acc);

  const int tid = threadIdx.x;
  const int w = tid >> 6, l = tid & 63, lr = l & 15, lg = l >> 4;
  const int wm = w >> 1, wn = w & 1;
#pragma unroll
  for (int fm = 0; fm < 2; ++fm)
#pragma unroll
    for (int fn = 0; fn < 4; ++fn)
#pragma unroll
      for (int r = 0; r < 4; ++r) {
        const int m = m0 + wm * 32 + fm * 16 + lg * 4 + r;
        const int n = n0 + wn * 64 + fn * 16 + lr;
        const size_t idx = (size_t)m * 1024 + n;
        x[idx] = acc[fm][fn][r] + bo[n] + resid[idx];
      }
}

// ---------- softmax denominator PARTIALS, j-split ----------
// R18: 1024 blocks (XCD-swizzled) = 32 bh x 16 it x 2 jh. Each block sums
// exp over its 1024-j half (16 tile iterations instead of 32) and writes
// Ld[jh][bh][row]. Doubles occupancy-level parallelism (4 blocks/CU,
// 16 waves/CU) and halves the serial tile-loop depth. attn3 adds the two
// halves in fixed order -> deterministic.
__global__ __launch_bounds__(256, 4) void denom_kernel(
    const u16* __restrict__ Qb, const u16* __restrict__ Kb,
    float* __restrict__ Ld) {
  __shared__ u16 Kbuf[2][4096];   // [64 j][64 d] bf16, swizzled
  const int tid = threadIdx.x;
  const int w = tid >> 6, l = tid & 63, lr = l & 15, lg = l >> 4;

  int flat = blockIdx.x;
  flat = (flat & 7) * 128 + (flat >> 3);  // bijective XCD swizzle (1024=8*128)
  const int it = flat & 15, jh = (flat >> 4) & 1, bh = flat >> 5;
  const int i0 = it * 128, jbase = jh * 1024;

  const char* KhB = (const char*)(Kb + (size_t)bh * 2048 * 64);
  const u16* Q0 = Qb + ((size_t)bh * 2048 + i0 + w * 32 + lr) * 64;
  const bf16x8 q00 = *(const bf16x8*)(Q0 + lg * 8);
  const bf16x8 q01 = *(const bf16x8*)(Q0 + 32 + lg * 8);
  const bf16x8 q10 = *(const bf16x8*)(Q0 + 16 * 64 + lg * 8);
  const bf16x8 q11 = *(const bf16x8*)(Q0 + 16 * 64 + 32 + lg * 8);

  const int srow = l >> 3;
  const int soff = ((l & 7) ^ srow) << 4;
  const int rsw = (lr & 7) << 4;

#define STAGE_K(bb, j0)                                                      \
  load_lds16(KhB + (size_t)((j0) + w * 8 + srow) * 128 + soff,               \
             (char*)Kbuf[bb] + w * 1024);                                    \
  load_lds16(KhB + (size_t)((j0) + 32 + w * 8 + srow) * 128 + soff,          \
             (char*)Kbuf[bb] + w * 1024 + 4096);

  f32x4 ls0 = (f32x4){0.f, 0.f, 0.f, 0.f}, ls1 = ls0;
  STAGE_K(0, jbase);
  __syncthreads();
  for (int jt = 0; jt < 16; ++jt) {
    const int bb = jt & 1;
    if (jt < 15) { STAGE_K(bb ^ 1, jbase + (jt + 1) * 64); }
    const char* kb = (const char*)Kbuf[bb];
#pragma unroll
    for (int t = 0; t < 4; ++t) {
      const bf16x8 k0 = *(const bf16x8*)(kb + (t * 16 + lr) * 128 + ((lg * 16) ^ rsw));
      const bf16x8 k1 = *(const bf16x8*)(kb + (t * 16 + lr) * 128 + ((64 + lg * 16) ^ rsw));
      f32x4 c0 = (f32x4){0.f, 0.f, 0.f, 0.f}, c1 = c0;
      c0 = __builtin_amdgcn_mfma_f32_16x16x32_bf16(k0, q00, c0, 0, 0, 0);
      c0 = __builtin_amdgcn_mfma_f32_16x16x32_bf16(k1, q01, c0, 0, 0, 0);
      c1 = __builtin_amdgcn_mfma_f32_16x16x32_bf16(k0, q10, c1, 0, 0, 0);
      c1 = __builtin_amdgcn_mfma_f32_16x16x32_bf16(k1, q11, c1, 0, 0, 0);
      ls0[0] += __expf(c0[0] * 0.125f);
      ls0[1] += __expf(c0[1] * 0.125f);
      ls0[2] += __expf(c0[2] * 0.125f);
      ls0[3] += __expf(c0[3] * 0.125f);
      ls1[0] += __expf(c1[0] * 0.125f);
      ls1[1] += __expf(c1[1] * 0.125f);
      ls1[2] += __expf(c1[2] * 0.125f);
      ls1[3] += __expf(c1[3] * 0.125f);
    }
    __syncthreads();
  }
#undef STAGE_K
  float s0 = ls0[0] + ls0[1] + ls0[2] + ls0[3];
  s0 += __shfl_xor(s0, 16);
  s0 += __shfl_xor(s0, 32);
  float s1 = ls1[0] + ls1[1] + ls1[2] + ls1[3];
  s1 += __shfl_xor(s1, 16);
  s1 += __shfl_xor(s1, 32);
  if (l < 16) {
    float* Lh = Ld + (size_t)jh * 65536 + (size_t)bh * 2048 + i0 + w * 32;
    Lh[l] = s0;
    Lh[16 + l] = s1;
  }
}

// ---------- fused attention, 8-wave blocks, triple-buffered tiles ----------
// Denominator = Ld[0][row] + Ld[1][row] (j-split partials, fixed order).
// R18 epilogue: O routed through the (now free) per-wave P slot -- 16
// ds_write_u16 + 2 ds_read_b128 + 2 global 16B stores with 128B-contiguous
// row segments, replacing 16 scalar u16 global stores at 32B spacing.
__global__ __launch_bounds__(512, 4) void attn3_kernel(
    const u16* __restrict__ Qb, const u16* __restrict__ Kb,
    const u16* __restrict__ Vt, const float* __restrict__ Ld,
    float* __restrict__ attnG, u16* __restrict__ outattn) {
  __shared__ u16 Kbuf[3][4096];   // [64 j][64 d] bf16, swizzled, 8KB each
  __shared__ u16 Vbuf[3][4096];   // [64 d][64 j] bf16, swizzled, 8KB each
  __shared__ u16 Pbuf[8][1024];   // per-wave [16 q][64 j] bf16, swizzled
  const int tid = threadIdx.x;
  const int w = tid >> 6, l = tid & 63, lr = l & 15, lg = l >> 4;

  int flat = (blockIdx.z * 16 + blockIdx.y) * 16 + blockIdx.x;
  flat = (flat & 7) * 64 + (flat >> 3);           // bijective XCD swizzle (512)
  const int qt = flat & 15, h = (flat >> 4) & 15, b = flat >> 8;
  const int bh = b * 16 + h;
  const int i0 = qt * 128 + w * 16;

  const char* KhB = (const char*)(Kb + (size_t)bh * 2048 * 64);
  const char* VhB = (const char*)(Vt + (size_t)bh * 64 * 2048);
  const u16* Qrow = Qb + ((size_t)bh * 2048 + i0 + lr) * 64;
  const bf16x8 bq0 = *(const bf16x8*)(Qrow + lg * 8);
  const bf16x8 bq1 = *(const bf16x8*)(Qrow + 32 + lg * 8);
  const size_t lidx = (size_t)bh * 2048 + i0 + lr;
  const float inv = 1.f / (Ld[lidx] + Ld[65536 + lidx]);

  const int srow = l >> 3;                 // row-within-8 for this lane
  const int soff = ((l & 7) ^ srow) << 4;  // logical byte offset fetched
  const int rsw = (lr & 7) << 4;           // read-side swizzle for frags

  // 8 waves cover the full 64 rows of each tile: wave w -> rows w*8+srow.
#define STAGE_K(bb, j0)                                                      \
  load_lds16(KhB + (size_t)((j0) + w * 8 + srow) * 128 + soff,               \
             (char*)Kbuf[bb] + w * 1024);
#define STAGE_V(bb, j0)                                                      \
  load_lds16(VhB + (size_t)(w * 8 + srow) * 4096 + (size_t)(j0) * 2 + soff,  \
             (char*)Vbuf[bb] + w * 1024);

  // coalesced attn store base: lane l -> row (l>>4), col (l&15)*4
  float* const awb = attnG + ((size_t)bh * 2048 + i0 + (l >> 4)) * 2048 + (l & 15) * 4;
  char* const Pw = (char*)Pbuf[w];
  f32x4 o0 = (f32x4){0.f, 0.f, 0.f, 0.f}, o1 = o0, o2 = o0, o3 = o0;

  STAGE_K(0, 0);
  STAGE_V(0, 0);
  STAGE_K(1, 64);
  STAGE_V(1, 64);
  __syncthreads();
  for (int jt = 0; jt < 32; ++jt) {
    const int bb = jt % 3;
    if (jt < 30) {
      const int sb = (jt + 2) % 3;
      STAGE_K(sb, (jt + 2) * 64);
      STAGE_V(sb, (jt + 2) * 64);
    }
    const char* kb = (const char*)Kbuf[bb];
    const char* vb = (const char*)Vbuf[bb];
    const int j0 = jt * 64;
    // scores -> P (bf16, swizzled LDS)
#pragma unroll
    for (int t = 0; t < 4; ++t) {
      const bf16x8 k0 = *(const bf16x8*)(kb + (t * 16 + lr) * 128 + ((lg * 16) ^ rsw));
      const bf16x8 k1 = *(const bf16x8*)(kb + (t * 16 + lr) * 128 + ((64 + lg * 16) ^ rsw));
      f32x4 c = (f32x4){0.f, 0.f, 0.f, 0.f};
      c = __builtin_amdgcn_mfma_f32_16x16x32_bf16(k0, bq0, c, 0, 0, 0);
      c = __builtin_amdgcn_mfma_f32_16x16x32_bf16(k1, bq1, c, 0, 0, 0);
      u16x4 pu;
      pu[0] = f2bf(__expf(c[0] * 0.125f) * inv);
      pu[1] = f2bf(__expf(c[1] * 0.125f) * inv);
      pu[2] = f2bf(__expf(c[2] * 0.125f) * inv);
      pu[3] = f2bf(__expf(c[3] * 0.125f) * inv);
      *(u16x4*)(Pw + lr * 128 + ((t * 32 + lg * 8) ^ rsw)) = pu;
    }
    // coalesced attn write-back from P: 4 instrs, each 4 x 256B contiguous
#pragma unroll
    for (int rq = 0; rq < 4; ++rq) {
      const int row = rq * 4 + (l >> 4);
      const u16x4 pb = *(const u16x4*)(Pw + row * 128 +
                                       (((l & 15) * 8) ^ ((row & 7) << 4)));
      f32x4 pf;
      pf[0] = __builtin_bit_cast(float, (unsigned)(unsigned short)pb[0] << 16);
      pf[1] = __builtin_bit_cast(float, (unsigned)(unsigned short)pb[1] << 16);
      pf[2] = __builtin_bit_cast(float, (unsigned)(unsigned short)pb[2] << 16);
      pf[3] = __builtin_bit_cast(float, (unsigned)(unsigned short)pb[3] << 16);
      __builtin_nontemporal_store(pf, (f32x4*)(awb + (size_t)(rq * 4) * 2048 + j0));
    }
    // PV (MFMA cluster -- setprio per T5)
    __builtin_amdgcn_s_setprio(1);
#pragma unroll
    for (int half = 0; half < 2; ++half) {
      const int jjb = half * 64;   // byte offset of 32-j half within P/V rows
      const bf16x8 pa = *(const bf16x8*)(Pw + lr * 128 + ((jjb + lg * 16) ^ rsw));
      const bf16x8 v0 = *(const bf16x8*)(vb + (0 * 16 + lr) * 128 + ((jjb + lg * 16) ^ rsw));
      const bf16x8 v1 = *(const bf16x8*)(vb + (1 * 16 + lr) * 128 + ((jjb + lg * 16) ^ rsw));
      const bf16x8 v2 = *(const bf16x8*)(vb + (2 * 16 + lr) * 128 + ((jjb + lg * 16) ^ rsw));
      const bf16x8 v3 = *(const bf16x8*)(vb + (3 * 16 + lr) * 128 + ((jjb + lg * 16) ^ rsw));
      o0 = __builtin_amdgcn_mfma_f32_16x16x32_bf16(pa, v0, o0, 0, 0, 0);
      o1 = __builtin_amdgcn_mfma_f32_16x16x32_bf16(pa, v1, o1, 0, 0, 0);
      o2 = __builtin_amdgcn_mfma_f32_16x16x32_bf16(pa, v2, o2, 0, 0, 0);
      o3 = __builtin_amdgcn_mfma_f32_16x16x32_bf16(pa, v3, o3, 0, 0, 0);
    }
    __builtin_amdgcn_s_setprio(0);
    // vmcnt(10): keep [4 stores jt][2 loads jt][4 stores jt-1] in flight;
    // drain loads(jt-1) (buffer for iter jt+1) and stores(jt-2).
    asm volatile("s_waitcnt vmcnt(10)" ::: "memory");
    __builtin_amdgcn_sched_barrier(0);
    __builtin_amdgcn_s_barrier();
  }
#undef STAGE_K
#undef STAGE_V

  // ---- O write via Pw staging: [16 rows][64 d] bf16, then coalesced
  // 16B stores (128B-contiguous row segments). Pw is wave-private; the
  // compiler orders the ds_write->ds_read pair via lgkmcnt.
  u16* const Pow = (u16*)Pw;
#pragma unroll
  for (int r = 0; r < 4; ++r) {
    const int row = lg * 4 + r;
    Pow[row * 64 + lr]      = f2bf(o0[r]);
    Pow[row * 64 + 16 + lr] = f2bf(o1[r]);
    Pow[row * 64 + 32 + lr] = f2bf(o2[r]);
    Pow[row * 64 + 48 + lr] = f2bf(o3[r]);
  }
#pragma unroll
  for (int p = 0; p < 2; ++p) {
    const int chunk = p * 64 + l;
    const int row = chunk >> 3, c8 = chunk & 7;
    const bf16x8 ov = *(const bf16x8*)(Pow + row * 64 + c8 * 8);
    *(bf16x8*)(outattn + ((size_t)b * 2048 + i0 + row) * 1024 + h * 64 + c8 * 8) = ov;
  }
}

// ---------- LayerNorm ----------
__global__ __launch_bounds__(256) void ln_kernel(const float* __restrict__ x,
                                                 const float* __restrict__ gamma,
                                                 const float* __restrict__ beta,
                                                 float* __restrict__ y) {
  const int row = blockIdx.x, t = threadIdx.x;
  const float4 xv = *(const float4*)(x + (size_t)row * 1024 + t * 4);
  float s = xv.x + xv.y + xv.z + xv.w;
  float q2 = xv.x * xv.x + xv.y * xv.y + xv.z * xv.z + xv.w * xv.w;
#pragma unroll
  for (int off = 32; off >= 1; off >>= 1) {
    s += __shfl_xor(s, off);
    q2 += __shfl_xor(q2, off);
  }
  __shared__ float ps[4], pq[4];
  const int w = t >> 6, l = t & 63;
  if (l == 0) { ps[w] = s; pq[w] = q2; }
  __syncthreads();
  s = ps[0] + ps[1] + ps[2] + ps[3];
  q2 = pq[0] + pq[1] + pq[2] + pq[3];
  const float mu = s * (1.f / 1024.f);
  const float var = q2 * (1.f / 1024.f) - mu * mu;
  const float rs = rsqrtf(var + 1e-5f);
  const float4 g = *(const float4*)(gamma + t * 4);
  const float4 bb = *(const float4*)(beta + t * 4);
  float4 o;
  o.x = (xv.x - mu) * rs * g.x + bb.x;
  o.y = (xv.y - mu) * rs * g.y + bb.y;
  o.z = (xv.z - mu) * rs * g.z + bb.z;
  o.w = (xv.w - mu) * rs * g.w + bb.w;
  *(float4*)(y + (size_t)row * 1024 + t * 4) = o;
}

// ---------- launch ----------
extern "C" void kernel_launch(void* const* d_in, const int* in_sizes, int n_in,
                              void* d_out, int out_size, void* d_ws, size_t ws_size,
                              hipStream_t stream) {
  (void)in_sizes; (void)n_in; (void)out_size; (void)ws_size;
  const float* q = (const float*)d_in[0];
  const float* k = (const float*)d_in[1];
  const float* v = (const float*)d_in[2];
  const float* Wq = (const float*)d_in[3];
  const float* bq = (const float*)d_in[4];
  const float* Wk = (const float*)d_in[5];
  const float* bk = (const float*)d_in[6];
  const float* Wv = (const float*)d_in[7];
  const float* bv = (const float*)d_in[8];
  const float* Wo = (const float*)d_in[9];
  const float* bo = (const float*)d_in[10];
  const float* gamma = (const float*)d_in[11];
  const float* beta = (const float*)d_in[12];

  char* ws = (char*)d_ws;
  const size_t MB = 1ull << 20;
  u16* WqT = (u16*)(ws + 0 * MB);
  u16* WkT = (u16*)(ws + 2 * MB);
  u16* WvT = (u16*)(ws + 4 * MB);
  u16* WoT = (u16*)(ws + 6 * MB);
  u16* qb  = (u16*)(ws + 8 * MB);
  float* Ld = (float*)(ws + 10 * MB);   // 2 x 32 x 2048 f32 = 512KB
  u16* kb  = (u16*)(ws + 16 * MB);
  u16* vb  = (u16*)(ws + 24 * MB);
  u16* Qb  = (u16*)(ws + 32 * MB);
  u16* Kb  = (u16*)(ws + 40 * MB);
  u16* Vt  = (u16*)(ws + 48 * MB);
  u16* oa  = (u16*)(ws + 56 * MB);
  float* x = (float*)(ws + 64 * MB);

  float* y = (float*)d_out;
  float* attnG = y + 4194304;  // 2*2048*1024

  prep_kernel<<<dim3(4096, 4), 256, 0, stream>>>(q, k, v, qb, kb, vb,
                                                 Wq, Wk, Wv, Wo,
                                                 WqT, WkT, WvT, WoT);
  qkv_gemm<<<dim3(32, 8, 3), 256, 0, stream>>>(qb, kb, vb, WqT, WkT, WvT,
                                               bq, bk, bv, Qb, Kb, Vt);
  denom_kernel<<<1024, 256, 0, stream>>>(Qb, Kb, Ld);
  attn3_kernel<<<dim3(16, 16, 2), 512, 0, stream>>>(Qb, Kb, Vt, Ld, attnG, oa);
  o_gemm<<<dim3(64, 8), 256, 0, stream>>>(oa, WoT, bo, q, x);
  ln_kernel<<<4096, 256, 0, stream>>>(x, gamma, beta, y);
}